// Round 7
// baseline (400.877 us; speedup 1.0000x reference)
//
#include <hip/hip_runtime.h>
#include <hip/hip_bf16.h>
#include <cstdint>

// B=8, S=2048, D=1024 single-head attention with QKV projection.
// R7: two-level XOR swizzle p = gk ^ ((r ^ (r>>3)) & 7) to kill the 4-way
// LDS column conflicts R6 measured (9.4M cyc = exactly 4/read). lsum zeroing
// folded into prep. Core: 32x32x16 bf16 MFMA, 128x256 block, BK=64, 4 waves,
// wave tile 64x128 (2x4 floatx16 acc), global_load_lds w=16 staging.

#define Bb 8
#define Ss 2048
#define Dd 1024

typedef unsigned short ushort_t;
typedef __attribute__((ext_vector_type(8))) short short8;
typedef __attribute__((ext_vector_type(16))) float floatx16;

__device__ inline ushort_t f2bf(float f) {
    unsigned int u = __float_as_uint(f);
    unsigned int r = (u + 0x7fffu + ((u >> 16) & 1u)) >> 16;
    return (ushort_t)r;
}
__device__ inline float bf2f(ushort_t u) {
    return __uint_as_float(((unsigned int)u) << 16);
}

__device__ inline floatx16 mfma32(short8 a, short8 b, floatx16 c) {
    return __builtin_amdgcn_mfma_f32_32x32x16_bf16(a, b, c, 0, 0, 0);
}

__device__ inline void gload_lds16(const void* g, void* l) {
    __builtin_amdgcn_global_load_lds(
        (const __attribute__((address_space(1))) void*)g,
        (__attribute__((address_space(3))) void*)l, 16, 0, 0);
}

// ---------------------------------------------------------------------------
// NT GEMM core: acc[2][4] += A[128 rows] * B[256 rows]^T over K, BK=64.
// LDS row = 64 elems (128 B). Swizzle: position p of row r holds global
// k-chunk p ^ sw(r), sw(r) = (r ^ (r>>3)) & 7.
// Staging (DMA): instr j of wave w covers rows base+j*8+srow; lane's global
// chunk = (lane&7) ^ srow ^ rowgrp_j  (rowgrp = (r>>3)&7, instr-uniform).
// Fragment read: pos = (2*step + h) ^ sw(r) -> same-column lanes differ in
// both nloc&7 and nloc>>3 (R5-style decorrelation).
// ---------------------------------------------------------------------------
__device__ __attribute__((always_inline)) void gemm_core32(
    const ushort_t* __restrict__ A, const ushort_t* __restrict__ B,
    int K, int lda, int ldb, int m0, int n0, int tid,
    ushort_t* As, ushort_t* Bs, floatx16 acc[2][4])
{
    const int lane = tid & 63;
    const int wave = tid >> 6;
    const int nloc = lane & 31;
    const int h    = lane >> 5;
    const int wm   = (wave & 1) * 64;
    const int wn   = (wave >> 1) * 128;

    const int srow = lane >> 3;   // 0..7
    const int xr   = lane & 7;

    // per-instr staging pointers (chunk varies with j via the row-group fold)
    const ushort_t* aPtr[4];
    const ushort_t* bPtr[8];
#pragma unroll
    for (int j = 0; j < 4; j++) {
        const int cg = xr ^ srow ^ ((wave * 4 + j) & 7);
        aPtr[j] = A + (size_t)(m0 + wave * 32 + j * 8 + srow) * lda + cg * 8;
    }
#pragma unroll
    for (int j = 0; j < 8; j++) {
        const int cg = xr ^ srow ^ j;   // (w*8+j)&7 == j
        bPtr[j] = B + (size_t)(n0 + wave * 64 + j * 8 + srow) * ldb + cg * 8;
    }

    int rowA[2], swA[2], rowB[4], swB[4];
    const int a = nloc & 7, b = nloc >> 3;
#pragma unroll
    for (int mt = 0; mt < 2; mt++) {
        rowA[mt] = (wm + mt * 32 + nloc) * 64;
        swA[mt]  = a ^ ((4 * mt + b) & 7);
    }
#pragma unroll
    for (int nt = 0; nt < 4; nt++) {
        rowB[nt] = (wn + nt * 32 + nloc) * 64;
        swB[nt]  = a ^ ((4 * nt + b) & 7);
    }

    for (int kt = 0; kt < K; kt += 64) {
#pragma unroll
        for (int j = 0; j < 4; j++)
            gload_lds16(aPtr[j] + kt, &As[(wave * 4 + j) * 512]);
#pragma unroll
        for (int j = 0; j < 8; j++)
            gload_lds16(bPtr[j] + kt, &Bs[(wave * 8 + j) * 512]);
        __syncthreads();

#pragma unroll
        for (int step = 0; step < 4; step++) {
            const int gk = step * 2 + h;
            short8 aF[2], bF[4];
#pragma unroll
            for (int mt = 0; mt < 2; mt++)
                aF[mt] = *(const short8*)&As[rowA[mt] + ((gk ^ swA[mt]) << 3)];
#pragma unroll
            for (int nt = 0; nt < 4; nt++)
                bF[nt] = *(const short8*)&Bs[rowB[nt] + ((gk ^ swB[nt]) << 3)];
#pragma unroll
            for (int mt = 0; mt < 2; mt++)
#pragma unroll
                for (int nt = 0; nt < 4; nt++)
                    acc[mt][nt] = mfma32(aF[mt], bF[nt], acc[mt][nt]);
        }
        __syncthreads();
    }
}

// C/D layout (m74/m101): col = lane&31, row = (reg&3) + 8*(reg>>2) + 4*(lane>>5)
#define CD_ROW(reg, h) (((reg) & 3) + 8 * ((reg) >> 2) + 4 * (h))

// ---------------------------------------------------------------------------
// EPI 0: bf16 out, + aux[gc] bias (QKV).  EPI 3: fp32 out, * 1/aux[z*Ss+gr]
// ---------------------------------------------------------------------------
template <int EPI>
__global__ __launch_bounds__(256, 2) void gemm_nt(
    const ushort_t* __restrict__ A, const ushort_t* __restrict__ B,
    void* __restrict__ Cv, const float* __restrict__ aux,
    int K, int lda, int ldb, int ldc,
    size_t strideA, size_t strideB, size_t strideC)
{
    const int z = blockIdx.z;
    A += (size_t)z * strideA;
    B += (size_t)z * strideB;
    const int m0 = blockIdx.y * 128;
    const int n0 = blockIdx.x * 256;

    __shared__ __align__(16) ushort_t As[128 * 64];   // 16 KB
    __shared__ __align__(16) ushort_t Bs[256 * 64];   // 32 KB

    const int tid  = threadIdx.x;
    const int lane = tid & 63;
    const int wave = tid >> 6;
    const int nloc = lane & 31;
    const int h    = lane >> 5;
    const int wm   = (wave & 1) * 64;
    const int wn   = (wave >> 1) * 128;

    floatx16 acc[2][4] = {};
    gemm_core32(A, B, K, lda, ldb, m0, n0, tid, As, Bs, acc);

    if (EPI == 0) {
        ushort_t* Cb = (ushort_t*)Cv;
#pragma unroll
        for (int nt = 0; nt < 4; nt++) {
            const int gc = n0 + wn + nt * 32 + nloc;
            const float bval = aux[gc];
#pragma unroll
            for (int mt = 0; mt < 2; mt++)
#pragma unroll
                for (int reg = 0; reg < 16; reg++) {
                    const int gr = m0 + wm + mt * 32 + CD_ROW(reg, h);
                    Cb[(size_t)gr * ldc + gc] = f2bf(acc[mt][nt][reg] + bval);
                }
        }
    } else {
        float* Cf = (float*)Cv + (size_t)z * strideC;
#pragma unroll
        for (int mt = 0; mt < 2; mt++)
#pragma unroll
            for (int reg = 0; reg < 16; reg++) {
                const int gr = m0 + wm + mt * 32 + CD_ROW(reg, h);
                const float iv = 1.0f / aux[z * Ss + gr];
#pragma unroll
                for (int nt = 0; nt < 4; nt++) {
                    const int gc = n0 + wn + nt * 32 + nloc;
                    Cf[(size_t)gr * ldc + gc] = acc[mt][nt][reg] * iv;
                }
            }
    }
}

// ---------------------------------------------------------------------------
// Combined: blocks [0,1024) = score gemm (exp epilogue + rowsum atomics);
// blocks [1024,5120) = V-slice transpose QKVb -> Vt[b][d][s].
// ---------------------------------------------------------------------------
__global__ __launch_bounds__(256, 2) void score_vt(
    const ushort_t* __restrict__ QKVb, ushort_t* __restrict__ Pb,
    ushort_t* __restrict__ Vt, float* __restrict__ lsum)
{
    __shared__ __align__(16) ushort_t As[128 * 64];
    __shared__ __align__(16) ushort_t Bs[256 * 64];
    const int bid = blockIdx.x;
    const int tid = threadIdx.x;

    if (bid < 1024) {
        const int nb = bid & 7, mb = (bid >> 3) & 15, z = bid >> 7;
        const int m0 = mb * 128, n0 = nb * 256;
        const ushort_t* A = QKVb + (size_t)z * Ss * 3072;         // Q slice
        const ushort_t* B = A + 1024;                             // K slice

        floatx16 acc[2][4] = {};
        gemm_core32(A, B, Dd, 3072, 3072, m0, n0, tid, As, Bs, acc);

        const int lane = tid & 63, wave = tid >> 6;
        const int nloc = lane & 31, h = lane >> 5;
        const int wm = (wave & 1) * 64, wn = (wave >> 1) * 128;
        ushort_t* Cp = Pb + (size_t)z * Ss * Ss;

        float rs[2][16] = {};
#pragma unroll
        for (int nt = 0; nt < 4; nt++) {
            const int gc = n0 + wn + nt * 32 + nloc;
#pragma unroll
            for (int mt = 0; mt < 2; mt++)
#pragma unroll
                for (int reg = 0; reg < 16; reg++) {
                    const int gr = m0 + wm + mt * 32 + CD_ROW(reg, h);
                    const ushort_t o = f2bf(__expf(acc[mt][nt][reg] * 0.03125f));
                    Cp[(size_t)gr * Ss + gc] = o;
                    rs[mt][reg] += bf2f(o);
                }
        }
        // reduce over the 32 col-lanes of each half, then 1 atomic/row
#pragma unroll
        for (int mt = 0; mt < 2; mt++)
#pragma unroll
            for (int reg = 0; reg < 16; reg++) {
                float s = rs[mt][reg];
                s += __shfl_xor(s, 1);
                s += __shfl_xor(s, 2);
                s += __shfl_xor(s, 4);
                s += __shfl_xor(s, 8);
                s += __shfl_xor(s, 16);
                rs[mt][reg] = s;
            }
        if (nloc == 0) {
#pragma unroll
            for (int mt = 0; mt < 2; mt++)
#pragma unroll
                for (int reg = 0; reg < 16; reg++) {
                    const int gr = m0 + wm + mt * 32 + CD_ROW(reg, h);
                    atomicAdd(&lsum[z * Ss + gr], rs[mt][reg]);
                }
        }
    } else {
        // V transpose: 64x64 bf16 tiles, 512 per batch
        const int t = bid - 1024;
        const int z = t >> 9, rem = t & 511;
        const int d0 = (rem & 15) * 64, s0 = (rem >> 4) * 64;
        ushort_t (*tile)[72] = (ushort_t(*)[72])As;   // 9216 B
        const int rr = tid >> 3;          // 0..31
        const int c8 = (tid & 7) * 8;     // 0..56
#pragma unroll
        for (int i = 0; i < 2; i++) {
            const int s = s0 + rr + i * 32;
            uint4 v = *(const uint4*)&QKVb[((size_t)(z * Ss + s)) * 3072 + 2048 + d0 + c8];
            *(uint4*)&tile[rr + i * 32][c8] = v;
        }
        __syncthreads();
#pragma unroll
        for (int i = 0; i < 2; i++) {
            const int d = rr + i * 32;
            ushort_t u[8];
#pragma unroll
            for (int j = 0; j < 8; j++) u[j] = tile[c8 + j][d];
            *(uint4*)&Vt[(size_t)z * Dd * Ss + (size_t)(d0 + d) * Ss + s0 + c8] =
                *(const uint4*)u;
        }
    }
}

// ---------------------------------------------------------------------------
// prep: [0,8192) x fp32->bf16; [8192,8960) W^T cvt; 8960 bias concat;
// [8961,8977) zero lsum (16384 floats)
// ---------------------------------------------------------------------------
__global__ __launch_bounds__(256) void prep(
    const float* __restrict__ x,
    const float* __restrict__ W0, const float* __restrict__ W1,
    const float* __restrict__ W2,
    const float* __restrict__ bq, const float* __restrict__ bk,
    const float* __restrict__ bv,
    ushort_t* __restrict__ xb, ushort_t* __restrict__ Wall,
    float* __restrict__ ball, float* __restrict__ lsum)
{
    const int bid = blockIdx.x;
    const int tid = threadIdx.x;

    if (bid < 8192) {
        const size_t i = (size_t)bid * 256 + tid;
        const float4* p = (const float4*)x + i * 2;
        float4 a = p[0], b = p[1];
        ushort_t u[8];
        u[0]=f2bf(a.x); u[1]=f2bf(a.y); u[2]=f2bf(a.z); u[3]=f2bf(a.w);
        u[4]=f2bf(b.x); u[5]=f2bf(b.y); u[6]=f2bf(b.z); u[7]=f2bf(b.w);
        *(uint4*)(xb + i * 8) = *(const uint4*)u;
    } else if (bid < 8960) {
        const int t = bid - 8192;
        const int z = t >> 8;
        const float* W = (z == 0) ? W0 : (z == 1) ? W1 : W2;
        ushort_t* Wt = Wall + (size_t)z * Dd * Dd;
        __shared__ float tt[64][65];
        const int n0 = ((t >> 4) & 15) * 64, k0 = (t & 15) * 64;
        const int r  = tid >> 4;
        const int c4 = (tid & 15) * 4;
#pragma unroll
        for (int i = 0; i < 4; i++) {
            float4 v = *(const float4*)&W[(size_t)(k0 + r + i * 16) * Dd + n0 + c4];
            tt[r + i * 16][c4 + 0] = v.x;
            tt[r + i * 16][c4 + 1] = v.y;
            tt[r + i * 16][c4 + 2] = v.z;
            tt[r + i * 16][c4 + 3] = v.w;
        }
        __syncthreads();
#pragma unroll
        for (int i = 0; i < 4; i++) {
            const int rn = r + i * 16;
            ushort_t u[4];
#pragma unroll
            for (int j = 0; j < 4; j++) u[j] = f2bf(tt[c4 + j][rn]);
            *(uint2*)&Wt[(size_t)(n0 + rn) * Dd + k0 + c4] = *(const uint2*)u;
        }
    } else if (bid == 8960) {
#pragma unroll
        for (int j = 0; j < 12; j++) {
            const int idx = j * 256 + tid;
            float v = (idx < 1024) ? bq[idx]
                    : (idx < 2048) ? bk[idx - 1024] : bv[idx - 2048];
            ball[idx] = v;
        }
    } else {
        const int i = (bid - 8961) * 1024 + tid * 4;
        *(float4*)&lsum[i] = float4{0.f, 0.f, 0.f, 0.f};
    }
}

// ---------------------------------------------------------------------------
extern "C" void kernel_launch(void* const* d_in, const int* in_sizes, int n_in,
                              void* d_out, int out_size, void* d_ws, size_t ws_size,
                              hipStream_t stream)
{
    const float* x  = (const float*)d_in[0];
    const float* Wq = (const float*)d_in[1];
    const float* bq = (const float*)d_in[2];
    const float* Wk = (const float*)d_in[3];
    const float* bk = (const float*)d_in[4];
    const float* Wv = (const float*)d_in[5];
    const float* bv = (const float*)d_in[6];
    float* out = (float*)d_out;

    char* ws = (char*)d_ws;
    const size_t MB = 1u << 20;
    // ws: [0,32) xb (dead after QKV) / Vt; [32,128) QKVb[16384][3072] bf16;
    //     [128,192) Pb = expP bf16; [192,+64K) lsum fp32[16384]
    // d_out doubles as prep scratch (read only before any out write):
    //     Wall bf16[3072][1024] @ +0, ball fp32[3072] @ +6MB
    ushort_t* xb   = (ushort_t*)(ws);
    ushort_t* Vt   = (ushort_t*)(ws);
    ushort_t* QKVb = (ushort_t*)(ws + 32 * MB);
    ushort_t* Pb   = (ushort_t*)(ws + 128 * MB);
    float*    lsum = (float*)(ws + 192 * MB);
    ushort_t* Wall = (ushort_t*)d_out;
    float*    ball = (float*)((char*)d_out + 6 * MB);

    // 0) prep (incl. lsum zeroing)
    prep<<<8977, 256, 0, stream>>>(x, Wq, Wk, Wv, bq, bk, bv, xb, Wall, ball, lsum);

    // 1) fused QKV projection: M=16384, N=3072, K=1024
    dim3 g1(3072 / 256, (Bb * Ss) / 128, 1);
    gemm_nt<0><<<g1, 256, 0, stream>>>(xb, Wall, QKVb, ball,
                                       Dd, Dd, Dd, 3072, 0, 0, 0);

    // 2) scores(+exp,+rowsum) and V-transpose
    score_vt<<<5120, 256, 0, stream>>>(QKVb, Pb, Vt, lsum);

    // 3) out = (expP @ Vt^T) * 1/l : per-batch 2048x1024, K=2048, fp32 out
    dim3 g3(Dd / 256, Ss / 128, Bb);
    gemm_nt<3><<<g3, 256, 0, stream>>>(Pb, Vt, out, lsum,
                                       Ss, Ss, Ss, Dd,
                                       (size_t)Ss * Ss, (size_t)Dd * Ss,
                                       (size_t)Ss * Dd);
}